// Round 11
// baseline (248.383 us; speedup 1.0000x reference)
//
#include <hip/hip_runtime.h>

#define B_    2
#define T_    2048
#define C_    1024
#define H_    16
#define HD_   64
#define MEM_  256
#define S_    2304   // MEM + T
#define NKT_  36     // S_/64 k-tiles

typedef __attribute__((ext_vector_type(8))) short short8;   // 8 bf16 = 4 VGPRs
typedef __attribute__((ext_vector_type(4))) short short4v;  // 4 bf16 = 2 VGPRs
typedef __attribute__((ext_vector_type(4))) float f32x4;

// round-half-up bf16 (2 VALU ops; tie behavior irrelevant here)
__device__ __forceinline__ unsigned short f2bf(float x) {
    return (unsigned short)((__float_as_uint(x) + 0x8000u) >> 16);
}

// pack 2 floats -> 2 bf16 in one VGPR (round-half-up): 2 adds + 1 v_perm
__device__ __forceinline__ unsigned int pk2bf(float lo, float hi) {
    unsigned int a = __float_as_uint(lo) + 0x8000u;
    unsigned int b = __float_as_uint(hi) + 0x8000u;
    return __builtin_amdgcn_perm(b, a, 0x07060302);  // {b.hi16, a.hi16}
}

typedef const __attribute__((address_space(1))) unsigned int* gp_t;
typedef __attribute__((address_space(3))) unsigned int* lp_t;

// async global->LDS, 16B/lane. g per-lane (base + lane*8 ushorts), l wave-uniform.
__device__ __forceinline__ void gll16(const unsigned short* g, unsigned short* l) {
    __builtin_amdgcn_global_load_lds((gp_t)g, (lp_t)l, 16, 0, 0);
}

#define C1_ 0.18033688011112042f   // log2(e)/sqrt(64), pre-folded into q

// ---------------------------------------------------------------------------
// Merged prep: job by flat blockIdx.
//  [0,4096)       convert x  -> x_tl  tile-major swizzled [mt][kc][128][32]
//  [4096,4864)    transpose W_attn -> WtA [nt][kc][128][32]
//  [4864,5120)    transpose W_proj -> WtP
//  [5120,7168)    ext_mem -> k_ws rows 0..MEM (row-swz), v_tl tiles 0..3 (swz)
// ---------------------------------------------------------------------------
__global__ __launch_bounds__(256) void prep_all(
    const float* __restrict__ x, const float* __restrict__ Wa,
    const float* __restrict__ Wp, const float* __restrict__ ext,
    unsigned short* __restrict__ x_tl, unsigned short* __restrict__ WtA,
    unsigned short* __restrict__ WtP, unsigned short* __restrict__ k_ws,
    unsigned short* __restrict__ v_tl)
{
    __shared__ float L[64][65];
    const int bid = blockIdx.x, tid = threadIdx.x;
    if (bid < 4096) {
        int i = bid * 256 + tid;                  // over 1,048,576 float4
        int c = (i & 255) * 4;
        int m = i >> 8;
        float4 v = ((const float4*)x)[i];
        ushort4 o;
        o.x = f2bf(v.x); o.y = f2bf(v.y); o.z = f2bf(v.z); o.w = f2bf(v.w);
        int mt = m >> 7, r = m & 127, kc = c >> 5, cc = c & 31;
        int p = (cc >> 3) ^ ((r >> 1) & 3);
        *(ushort4*)&x_tl[(((size_t)mt * 32 + kc) << 12) + (r << 5) + p * 8 + (cc & 7)] = o;
    } else if (bid < 5120) {
        const float* in; unsigned short* out; int Cc, r0, c0;
        if (bid < 4864) {
            int r = bid - 4096; in = Wa; out = WtA; Cc = 3 * C_;
            c0 = (r % 48) * 64; r0 = (r / 48) * 64;
        } else {
            int r = bid - 4864; in = Wp; out = WtP; Cc = C_;
            c0 = (r & 15) * 64; r0 = (r >> 4) * 64;
        }
        const int jj = tid >> 4;
        const int i4 = (tid & 15) * 4;
#pragma unroll
        for (int t = 0; t < 4; ++t) {
            int j = jj + t * 16;
            float4 v = *(const float4*)(in + (size_t)(r0 + j) * Cc + c0 + i4);
            L[i4 + 0][j] = v.x; L[i4 + 1][j] = v.y;
            L[i4 + 2][j] = v.z; L[i4 + 3][j] = v.w;
        }
        __syncthreads();
#pragma unroll
        for (int t = 0; t < 4; ++t) {
            int n = c0 + jj + t * 16;
            int k = r0 + i4;
            ushort4 o;
            o.x = f2bf(L[jj + t * 16][i4 + 0]); o.y = f2bf(L[jj + t * 16][i4 + 1]);
            o.z = f2bf(L[jj + t * 16][i4 + 2]); o.w = f2bf(L[jj + t * 16][i4 + 3]);
            int nt = n >> 7, r = n & 127, kc = k >> 5, cc = k & 31;
            int p = (cc >> 3) ^ ((r >> 1) & 3);
            *(ushort4*)&out[(((size_t)nt * 32 + kc) << 12) + (r << 5) + p * 8 + (cc & 7)] = o;
        }
    } else {
        int idx = (bid - 5120) * 256 + tid;       // < B*MEM*C = 524288
        float val = ext[idx];
        int c = idx & (C_ - 1), m = (idx >> 10) & (MEM_ - 1), b = idx >> 18;
        int h = c >> 6, d = c & 63;
        int bh = b * H_ + h;
        unsigned short bv = f2bf(val);
        k_ws[(size_t)bh * S_ * 64 + (size_t)m * 64 + (((d >> 3) ^ (m & 7)) << 3) + (d & 7)] = bv;
        int ts = m >> 6, key = m & 63;
        v_tl[(((size_t)bh * NKT_ + ts) * 64 + d) * 64 + (((key >> 3) ^ (d & 7)) << 3) + (key & 7)] = bv;
    }
}

// ---------------------------------------------------------------------------
// QKV GEMM: bf16 MFMA on tile-major pre-swizzled inputs, async
// global_load_lds, double-buffered LDS, 1 barrier/k-chunk. 128x128 tile,
// BK=32, 4 waves. Epilogue scatters q natural (PRE-SCALED by log2(e)/8 so
// flash skips the per-score multiply), k row-swizzled, v tile-major.
// v18: XCD remap REVERTED (A/B: v17's remap region = 5MB > 4MB L2, couldn't
// deliver residency; rest-of-pipeline rose 135.6->141.6us when added).
// ---------------------------------------------------------------------------
__global__ __launch_bounds__(256) void qkv_gemm(
    const unsigned short* __restrict__ A,     // [32][32][128][32]
    const unsigned short* __restrict__ Bt,    // [24][32][128][32]
    const float* __restrict__ bias,
    unsigned short* __restrict__ q_ws,
    unsigned short* __restrict__ k_ws,
    unsigned short* __restrict__ v_tl)
{
    __shared__ __align__(16) unsigned short As[2][4096];
    __shared__ __align__(16) unsigned short Bs[2][4096];
    const int tid = threadIdx.x, lane = tid & 63, wave = tid >> 6;
    const int wr = wave >> 1, wc = wave & 1;
    const size_t abase = (size_t)blockIdx.y * 32 * 4096;
    const size_t bbase = (size_t)blockIdx.x * 32 * 4096;

    f32x4 acc[4][4];
#pragma unroll
    for (int i = 0; i < 4; ++i)
#pragma unroll
        for (int j = 0; j < 4; ++j) acc[i][j] = (f32x4){0.f, 0.f, 0.f, 0.f};

    auto stage = [&](int kc, int buf) {
        const unsigned short* ga = A + abase + (size_t)kc * 4096;
        const unsigned short* gb = Bt + bbase + (size_t)kc * 4096;
#pragma unroll
        for (int s = 0; s < 2; ++s) {
            int seg = wave + s * 4;                       // 0..7
            gll16(ga + seg * 512 + lane * 8, &As[buf][seg * 512]);
            gll16(gb + seg * 512 + lane * 8, &Bs[buf][seg * 512]);
        }
    };

    stage(0, 0);
    __syncthreads();
    for (int kc = 0; kc < 32; ++kc) {
        if (kc + 1 < 32) stage(kc + 1, (kc + 1) & 1);
        const unsigned short* as = As[kc & 1];
        const unsigned short* bs = Bs[kc & 1];
        short8 af[4], bf4[4];
#pragma unroll
        for (int i = 0; i < 4; ++i) {
            int row = wr * 64 + i * 16 + (lane & 15);
            int ph = (lane >> 4) ^ ((row >> 1) & 3);
            af[i] = *(const short8*)&as[row * 32 + ph * 8];
        }
#pragma unroll
        for (int j = 0; j < 4; ++j) {
            int row = wc * 64 + j * 16 + (lane & 15);
            int ph = (lane >> 4) ^ ((row >> 1) & 3);
            bf4[j] = *(const short8*)&bs[row * 32 + ph * 8];
        }
#pragma unroll
        for (int i = 0; i < 4; ++i)
#pragma unroll
            for (int j = 0; j < 4; ++j)
                acc[i][j] = __builtin_amdgcn_mfma_f32_16x16x32_bf16(
                    af[i], bf4[j], acc[i][j], 0, 0, 0);
        __syncthreads();
    }

#pragma unroll
    for (int j = 0; j < 4; ++j) {
        int n = blockIdx.x * 128 + wc * 64 + j * 16 + (lane & 15);
        float bs = bias[n];
        int sel = n >> 10, h = (n >> 6) & 15, d = n & 63;
#pragma unroll
        for (int i = 0; i < 4; ++i) {
            int m = blockIdx.y * 128 + wr * 64 + i * 16 + (lane >> 4) * 4;
            int b = m >> 11, t0 = m & (T_ - 1);
            int bh = b * H_ + h;
            if (sel == 0) {
                size_t base = ((size_t)bh * T_ + t0) * 64 + d;
#pragma unroll
                for (int r = 0; r < 4; ++r)
                    q_ws[base + (size_t)r * 64] = f2bf((acc[i][j][r] + bs) * C1_);
            } else if (sel == 1) {
#pragma unroll
                for (int r = 0; r < 4; ++r) {
                    int s = MEM_ + t0 + r;
                    k_ws[(size_t)bh * S_ * 64 + (size_t)s * 64
                         + (((d >> 3) ^ (s & 7)) << 3) + (d & 7)] =
                        f2bf(acc[i][j][r] + bs);
                }
            } else {
                int s0 = MEM_ + t0, ts = s0 >> 6, key = s0 & 63;
                ushort4 pv;
                pv.x = f2bf(acc[i][j][0] + bs);
                pv.y = f2bf(acc[i][j][1] + bs);
                pv.z = f2bf(acc[i][j][2] + bs);
                pv.w = f2bf(acc[i][j][3] + bs);
                *(ushort4*)&v_tl[(((size_t)bh * NKT_ + ts) * 64 + d) * 64
                                 + (((key >> 3) ^ (d & 7)) << 3) + (key & 7)] = pv;
            }
        }
    }
}

// ---------------------------------------------------------------------------
// Proj GEMM: 64x128 tiles -> 512 blocks (2/CU, 2 waves/SIMD). 4 waves; wave w
// owns n-cols [w*32, w*32+32): 4 A-frags + 2 B-frags, 8 MFMA/chunk.
// v17 XCD remap KEPT (region footprint 3MB <= 4MB L2 — sound).
// ---------------------------------------------------------------------------
__global__ __launch_bounds__(256) void proj_gemm(
    const unsigned short* __restrict__ A,     // y_tl [32][32][128][32]
    const unsigned short* __restrict__ Bt,    // WtP  [8][32][128][32]
    const float* __restrict__ bias,
    float* __restrict__ out)
{
    __shared__ __align__(16) unsigned short As[2][2048];
    __shared__ __align__(16) unsigned short Bs[2][4096];
    const int tid = threadIdx.x, lane = tid & 63, wave = tid >> 6;
    // XCD-aware remap: flat&7 = xcd; 8x8 region per XCD.
    const int flat = blockIdx.x + 8 * blockIdx.y;
    const int xcd = flat & 7, i6 = flat >> 3;          // i6 in [0,64)
    const int bx = i6 & 7;                              // 0..7 (N dim)
    const int m64 = xcd * 8 + (i6 >> 3);                // 0..63 (M dim)
    const size_t abase = ((size_t)(m64 >> 1) * 32) * 4096 + (size_t)(m64 & 1) * 2048;
    const size_t bbase = (size_t)bx * 32 * 4096;

    f32x4 acc[4][2];
#pragma unroll
    for (int i = 0; i < 4; ++i)
#pragma unroll
        for (int j = 0; j < 2; ++j) acc[i][j] = (f32x4){0.f, 0.f, 0.f, 0.f};

    auto stage = [&](int kc, int buf) {
        const unsigned short* ga = A + abase + (size_t)kc * 4096;
        const unsigned short* gb = Bt + bbase + (size_t)kc * 4096;
        gll16(ga + wave * 512 + lane * 8, &As[buf][wave * 512]);
        gll16(gb + wave * 512 + lane * 8, &Bs[buf][wave * 512]);
        gll16(gb + (wave + 4) * 512 + lane * 8, &Bs[buf][(wave + 4) * 512]);
    };

    stage(0, 0);
    __syncthreads();
    for (int kc = 0; kc < 32; ++kc) {
        if (kc + 1 < 32) stage(kc + 1, (kc + 1) & 1);
        const unsigned short* as = As[kc & 1];
        const unsigned short* bs = Bs[kc & 1];
        short8 af[4], bf2[2];
#pragma unroll
        for (int i = 0; i < 4; ++i) {
            int row = i * 16 + (lane & 15);           // local row in 64-tile
            int ph = (lane >> 4) ^ ((row >> 1) & 3);  // (64+row) swizzle == row swizzle
            af[i] = *(const short8*)&as[row * 32 + ph * 8];
        }
#pragma unroll
        for (int j = 0; j < 2; ++j) {
            int row = wave * 32 + j * 16 + (lane & 15);
            int ph = (lane >> 4) ^ ((row >> 1) & 3);
            bf2[j] = *(const short8*)&bs[row * 32 + ph * 8];
        }
#pragma unroll
        for (int i = 0; i < 4; ++i)
#pragma unroll
            for (int j = 0; j < 2; ++j)
                acc[i][j] = __builtin_amdgcn_mfma_f32_16x16x32_bf16(
                    af[i], bf2[j], acc[i][j], 0, 0, 0);
        __syncthreads();
    }

#pragma unroll
    for (int j = 0; j < 2; ++j) {
        int n = bx * 128 + wave * 32 + j * 16 + (lane & 15);
        float bs = bias[n];
#pragma unroll
        for (int i = 0; i < 4; ++i) {
            int m = m64 * 64 + i * 16 + (lane >> 4) * 4;
#pragma unroll
            for (int r = 0; r < 4; ++r)
                out[(size_t)(m + r) * C_ + n] = acc[i][j][r] + bs;
        }
    }
}

// ---------------------------------------------------------------------------
// Flash attention v18 = v17 (XCD decode FETCH 75->13MB; denom on matrix pipe;
// running staging pointers; native exp2; top-stage discipline, absmax
// fingerprint 1.953e-3) + micro:
//  a. merge stride 20 -> 21 floats (gcd(21,32)=1: conflict-free strided LDS).
//  b. setprio(1) narrowed to the MFMA/exp cluster only (ds_read issue at
//     prio 0, HK placement).
//  c. phase-2 staging while -> branchless dual-if (max 2 stages/step).
// Note: SQ_LDS_BANK_CONFLICT = 5373952 = exactly 64 cyc/wave-tile = 8 b128
// reads x 8 cyc — irreducible wave64 read cost, NOT fixable conflicts (bank
// map of kA/vF is balanced). Step count 21 is near-optimal (41 works / 42
// slots); barrier-halving designs all fail LDS capacity or CU balance.
// ---------------------------------------------------------------------------
__global__ __launch_bounds__(512, 4) void flash_mfma(
    const unsigned short* __restrict__ qg,    // [bh][t][64] natural, pre-scaled
    const unsigned short* __restrict__ kg,    // [bh][s][64] row-swizzled
    const unsigned short* __restrict__ vg,    // [bh][36][64][64] key-swizzled
    unsigned short* __restrict__ yt)          // proj-tiled [mt][kc][128][32]
{
    __shared__ __align__(16) unsigned short Ks[4][4096];
    __shared__ __align__(16) unsigned short Vs[4][4096];

    const int tid = threadIdx.x, lane = tid & 63, w = tid >> 6;   // wave 0..7
    const int grp = w >> 2, wq = w & 3;
    const int quad = lane >> 4;
    // XCD-aware decode (round-robin flat%8 -> XCD; validated by v16 FETCH)
    const int flat = blockIdx.x + 16 * (blockIdx.y + 16 * blockIdx.z);
    const int xcd = flat & 7;
    const int kk = flat >> 3;                  // 0..63
    const int a = kk & 15;
    const int g8 = (kk >> 4) * 8 + xcd;        // bh-group 0..31
    const int h = g8 & 15, b = g8 >> 4;
    const int p0 = 5 + a;                      // short tile's k-tile count
    const int nl = 36 - a;                     // long tile's k-tile count
    const int n2 = nl - p0;                    // phase-2 tiles (31-2a, odd)
    const int qt = grp ? (31 - a) : a;         // this group's primary q-tile
    const int bh = b * H_ + h;
    const size_t kgb = (size_t)bh * S_ * 64;
    const size_t vgb = (size_t)bh * NKT_ * 4096;

    // Primary Q fragment (B-operand layout: q=lane&15, d=quad*8+hf*32+j)
    short8 qfP[2], qf2[2];
    {
        const unsigned short* p = qg + ((size_t)bh * T_ + qt * 64 + wq * 16
                                        + (lane & 15)) * 64 + quad * 8;
        qfP[0] = *(const short8*)p; qfP[1] = *(const short8*)(p + 32);
        const unsigned short* q2 = qg + ((size_t)bh * T_ + (31 - a) * 64 + wq * 16
                                         + (lane & 15)) * 64 + quad * 8;
        qf2[0] = *(const short8*)q2; qf2[1] = *(const short8*)(q2 + 32);
    }

    f32x4 o[4], o2[4];
#pragma unroll
    for (int j = 0; j < 4; ++j) {
        o[j] = (f32x4){0.f, 0.f, 0.f, 0.f};
        o2[j] = (f32x4){0.f, 0.f, 0.f, 0.f};
    }
    f32x4 lv  = (f32x4){0.f, 0.f, 0.f, 0.f};   // denom, rows quad*4+r (MFMA acc)
    f32x4 lv2 = (f32x4){0.f, 0.f, 0.f, 0.f};

    short4v ones;                               // 4 x bf16 1.0
    {
        unsigned int oo1 = 0x3F803F80u;
        *(unsigned int*)&ones = oo1;
        *((unsigned int*)&ones + 1) = oo1;
    }

    // Loop-invariant LDS base pointers (ushort units).
    const unsigned short* kB0 = &Ks[0][(lane & 15) * 64 + ((quad ^ (lane & 7)) * 8)];
    const unsigned short* kB1 = &Ks[0][(lane & 15) * 64 + (((quad + 4) ^ (lane & 7)) * 8)];
    const unsigned short* vPs[4];
#pragma unroll
    for (int kb = 0; kb < 4; ++kb)
        vPs[kb] = &Vs[0][(lane & 15) * 64
                         + (((kb * 2 + (lane >> 5)) ^ (lane & 7)) * 8)
                         + (quad & 1) * 4];

    // running staging pointers (advance 4096 per staged tile)
    const unsigned short* gkC = kg + kgb + (size_t)w * 512 + (size_t)lane * 8;
    const unsigned short* gvC = vg + vgb + (size_t)w * 512 + (size_t)lane * 8;

    auto stageCur = [&](int kt) {              // 8 waves: 1 gll K + 1 gll V each
        const int bf = kt & 3;
        gll16(gkC, &Ks[bf][w * 512]);
        gll16(gvC, &Vs[bf][w * 512]);
        gkC += 4096; gvC += 4096;
    };

    const int tqP = qt * 64 + wq * 16 + (lane & 15);        // primary query row
    const int tq2 = (31 - a) * 64 + wq * 16 + (lane & 15);  // grp0 phase-2 row

    auto computeTile = [&](int kt, const short8 (&qf)[2], f32x4 (&oo)[4],
                           f32x4& lacc, bool diag, int tq) {
        const int B = (kt & 3) << 12;          // buffer offset, ushorts
        const int s0 = kt * 64;
        short8 kA[4][2];
#pragma unroll
        for (int kb = 0; kb < 4; ++kb) {
            kA[kb][0] = *(const short8*)&kB0[B + kb * 1024];
            kA[kb][1] = *(const short8*)&kB1[B + kb * 1024];
        }
        short4v vF[4][4];
#pragma unroll
        for (int kb = 0; kb < 4; ++kb)
#pragma unroll
            for (int dblk = 0; dblk < 4; ++dblk)
                vF[kb][dblk] = *(const short4v*)&vPs[kb][B + dblk * 1024];

        __builtin_amdgcn_s_setprio(1);
#pragma unroll
        for (int kb = 0; kb < 4; ++kb) {
            f32x4 z = (f32x4){0.f, 0.f, 0.f, 0.f};
            z = __builtin_amdgcn_mfma_f32_16x16x32_bf16(kA[kb][0], qf[0], z, 0, 0, 0);
            z = __builtin_amdgcn_mfma_f32_16x16x32_bf16(kA[kb][1], qf[1], z, 0, 0, 0);
            float p[4];
#pragma unroll
            for (int r = 0; r < 4; ++r) {
                float e = __builtin_amdgcn_exp2f(z[r]);   // q pre-scaled
                if (diag) {
                    int key = s0 + kb * 16 + quad * 4 + r;
                    if (key - MEM_ > tq) e = 0.f;
                }
                p[r] = e;
            }
            short4v pf;
            *(unsigned int*)&pf       = pk2bf(p[0], p[1]);
            *((unsigned int*)&pf + 1) = pk2bf(p[2], p[3]);
            // denom on the matrix pipe: row-sums of P (all lanes identical)
            lacc = __builtin_amdgcn_mfma_f32_16x16x16bf16_1k(
                pf, ones, lacc, 0, 0, 0);
#pragma unroll
            for (int dblk = 0; dblk < 4; ++dblk)
                oo[dblk] = __builtin_amdgcn_mfma_f32_16x16x16bf16_1k(
                    pf, vF[kb][dblk], oo[dblk], 0, 0, 0);
        }
        __builtin_amdgcn_s_setprio(0);
    };

    // prologue: stage tiles 0,1,2 (nl >= 21 always)
    stageCur(0); stageCur(1); stageCur(2);
    int cursor = 3;

    // Phase 1: steps s = 0..p0-1; both groups consume tile s.
    // Stage at TOP (after barrier, before compute) — required discipline.
    for (int s = 0; s < p0; ++s) {
        __syncthreads();
        if (cursor < nl && cursor <= s + 3) { stageCur(cursor); ++cursor; }
        computeTile(s, qfP, o, lv, (grp == 0) && (s == p0 - 1), tqP);
    }

    // Phase 2: long tile's remaining k-range, split even/odd between groups.
    const int nsteps2 = (n2 + 1) >> 1;
    for (int s2 = 0; s2 < nsteps2; ++s2) {
        __syncthreads();
        const int lim = p0 + 2 * s2 + 3;
        if (cursor < nl && cursor <= lim) { stageCur(cursor); ++cursor; }
        if (cursor < nl && cursor <= lim) { stageCur(cursor); ++cursor; }
        int t = p0 + 2 * s2 + grp;
        if (t < nl) {
            bool dg = (t == nl - 1);
            if (grp == 0) computeTile(t, qf2, o2, lv2, dg, tq2);
            else          computeTile(t, qfP, o, lv, dg, tqP);
        }
    }

    // Merge grp0's phase-2 partial into grp1 (same rows, same lane layout).
    // Stride 21 floats: gcd(21,32)=1 -> conflict-free strided access.
    __syncthreads();
    float* sm = (float*)&Ks[0][0];             // 256 slots x 21 f32 = 21504B
    if (grp == 0) {
        int idx = (wq * 64 + lane) * 21;
#pragma unroll
        for (int dblk = 0; dblk < 4; ++dblk)
#pragma unroll
            for (int r = 0; r < 4; ++r) sm[idx + dblk * 4 + r] = o2[dblk][r];
#pragma unroll
        for (int r = 0; r < 4; ++r) sm[idx + 16 + r] = lv2[r];
    }
    __syncthreads();
    if (grp == 1) {
        int idx = (wq * 64 + lane) * 21;
#pragma unroll
        for (int dblk = 0; dblk < 4; ++dblk)
#pragma unroll
            for (int r = 0; r < 4; ++r) o[dblk][r] += sm[idx + dblk * 4 + r];
#pragma unroll
        for (int r = 0; r < 4; ++r) lv[r] += sm[idx + 16 + r];
    }

    // epilogue: lv[r] holds the denom for row quad*4+r directly (no shfl).
    float linv[4];
#pragma unroll
    for (int r = 0; r < 4; ++r)
        linv[r] = 1.f / lv[r];
#pragma unroll
    for (int dblk = 0; dblk < 4; ++dblk) {
        int c = h * 64 + dblk * 16 + (lane & 15);
        int kc = c >> 5, cc = c & 31;
#pragma unroll
        for (int r = 0; r < 4; ++r) {
            int t = qt * 64 + wq * 16 + quad * 4 + r;
            int m = b * T_ + t;
            int mt = m >> 7, rr = m & 127;
            int p = (cc >> 3) ^ ((rr >> 1) & 3);
            yt[(((size_t)mt * 32 + kc) << 12) + (rr << 5) + p * 8 + (cc & 7)] =
                f2bf(o[dblk][r] * linv[r]);
        }
    }
}

extern "C" void kernel_launch(void* const* d_in, const int* in_sizes, int n_in,
                              void* d_out, int out_size, void* d_ws, size_t ws_size,
                              hipStream_t stream) {
    (void)in_sizes; (void)n_in; (void)out_size; (void)ws_size;
    const float* x      = (const float*)d_in[0];
    const float* ext    = (const float*)d_in[1];
    const float* W_attn = (const float*)d_in[2];
    const float* b_attn = (const float*)d_in[3];
    const float* W_proj = (const float*)d_in[4];
    const float* b_proj = (const float*)d_in[5];
    float* out = (float*)d_out;

    unsigned short* x_tl  = (unsigned short*)d_ws;           // [32][32][128][32]
    unsigned short* WtA   = x_tl + 4194304;                  // [24][32][128][32]
    unsigned short* WtP   = WtA + 3145728;                   // [8][32][128][32]
    unsigned short* q_ws  = WtP + 1048576;                   // [bh][t][64] pre-scaled
    unsigned short* k_ws  = q_ws + 4194304;                  // [bh][s][64] swz
    unsigned short* v_tl  = k_ws + 4718592;                  // [bh][36][64][64] swz
    unsigned short* y_tl  = v_tl + 4718592;                  // [32][32][128][32]

    dim3 blk(256);
    prep_all<<<7168, blk, 0, stream>>>(x, W_attn, W_proj, ext,
                                       x_tl, WtA, WtP, k_ws, v_tl);
    qkv_gemm<<<dim3(24, 32), blk, 0, stream>>>(
        x_tl, WtA, b_attn, q_ws, k_ws, v_tl);
    flash_mfma<<<dim3(16, H_, B_), dim3(512), 0, stream>>>(q_ws, k_ws, v_tl, y_tl);
    proj_gemm<<<dim3(8, 64), blk, 0, stream>>>(y_tl, WtP, b_proj, out);
}

// Round 12
// 186.196 us; speedup vs baseline: 1.3340x; 1.3340x over previous
//
#include <hip/hip_runtime.h>

#define B_    2
#define T_    2048
#define C_    1024
#define H_    16
#define HD_   64
#define MEM_  256
#define S_    2304   // MEM + T
#define NKT_  36     // S_/64 k-tiles

typedef __attribute__((ext_vector_type(8))) short short8;   // 8 bf16 = 4 VGPRs
typedef __attribute__((ext_vector_type(4))) short short4v;  // 4 bf16 = 2 VGPRs
typedef __attribute__((ext_vector_type(4))) float f32x4;

// round-half-up bf16 (2 VALU ops; tie behavior irrelevant here)
__device__ __forceinline__ unsigned short f2bf(float x) {
    return (unsigned short)((__float_as_uint(x) + 0x8000u) >> 16);
}

// pack 2 floats -> 2 bf16 in one VGPR (round-half-up): 2 adds + 1 v_perm
__device__ __forceinline__ unsigned int pk2bf(float lo, float hi) {
    unsigned int a = __float_as_uint(lo) + 0x8000u;
    unsigned int b = __float_as_uint(hi) + 0x8000u;
    return __builtin_amdgcn_perm(b, a, 0x07060302);  // {b.hi16, a.hi16}
}

typedef const __attribute__((address_space(1))) unsigned int* gp_t;
typedef __attribute__((address_space(3))) unsigned int* lp_t;

// async global->LDS, 16B/lane. g per-lane (base + lane*8 ushorts), l wave-uniform.
__device__ __forceinline__ void gll16(const unsigned short* g, unsigned short* l) {
    __builtin_amdgcn_global_load_lds((gp_t)g, (lp_t)l, 16, 0, 0);
}

#define C1_ 0.18033688011112042f   // log2(e)/sqrt(64), pre-folded into q

// ---------------------------------------------------------------------------
// Merged prep: job by flat blockIdx.
//  [0,4096)       convert x  -> x_tl  tile-major swizzled [mt][kc][128][32]
//  [4096,4864)    transpose W_attn -> WtA [nt][kc][128][32]
//  [4864,5120)    transpose W_proj -> WtP
//  [5120,7168)    ext_mem -> k_ws rows 0..MEM (row-swz), v_tl tiles 0..3 (swz)
// ---------------------------------------------------------------------------
__global__ __launch_bounds__(256) void prep_all(
    const float* __restrict__ x, const float* __restrict__ Wa,
    const float* __restrict__ Wp, const float* __restrict__ ext,
    unsigned short* __restrict__ x_tl, unsigned short* __restrict__ WtA,
    unsigned short* __restrict__ WtP, unsigned short* __restrict__ k_ws,
    unsigned short* __restrict__ v_tl)
{
    __shared__ float L[64][65];
    const int bid = blockIdx.x, tid = threadIdx.x;
    if (bid < 4096) {
        int i = bid * 256 + tid;                  // over 1,048,576 float4
        int c = (i & 255) * 4;
        int m = i >> 8;
        float4 v = ((const float4*)x)[i];
        ushort4 o;
        o.x = f2bf(v.x); o.y = f2bf(v.y); o.z = f2bf(v.z); o.w = f2bf(v.w);
        int mt = m >> 7, r = m & 127, kc = c >> 5, cc = c & 31;
        int p = (cc >> 3) ^ ((r >> 1) & 3);
        *(ushort4*)&x_tl[(((size_t)mt * 32 + kc) << 12) + (r << 5) + p * 8 + (cc & 7)] = o;
    } else if (bid < 5120) {
        const float* in; unsigned short* out; int Cc, r0, c0;
        if (bid < 4864) {
            int r = bid - 4096; in = Wa; out = WtA; Cc = 3 * C_;
            c0 = (r % 48) * 64; r0 = (r / 48) * 64;
        } else {
            int r = bid - 4864; in = Wp; out = WtP; Cc = C_;
            c0 = (r & 15) * 64; r0 = (r >> 4) * 64;
        }
        const int jj = tid >> 4;
        const int i4 = (tid & 15) * 4;
#pragma unroll
        for (int t = 0; t < 4; ++t) {
            int j = jj + t * 16;
            float4 v = *(const float4*)(in + (size_t)(r0 + j) * Cc + c0 + i4);
            L[i4 + 0][j] = v.x; L[i4 + 1][j] = v.y;
            L[i4 + 2][j] = v.z; L[i4 + 3][j] = v.w;
        }
        __syncthreads();
#pragma unroll
        for (int t = 0; t < 4; ++t) {
            int n = c0 + jj + t * 16;
            int k = r0 + i4;
            ushort4 o;
            o.x = f2bf(L[jj + t * 16][i4 + 0]); o.y = f2bf(L[jj + t * 16][i4 + 1]);
            o.z = f2bf(L[jj + t * 16][i4 + 2]); o.w = f2bf(L[jj + t * 16][i4 + 3]);
            int nt = n >> 7, r = n & 127, kc = k >> 5, cc = k & 31;
            int p = (cc >> 3) ^ ((r >> 1) & 3);
            *(ushort4*)&out[(((size_t)nt * 32 + kc) << 12) + (r << 5) + p * 8 + (cc & 7)] = o;
        }
    } else {
        int idx = (bid - 5120) * 256 + tid;       // < B*MEM*C = 524288
        float val = ext[idx];
        int c = idx & (C_ - 1), m = (idx >> 10) & (MEM_ - 1), b = idx >> 18;
        int h = c >> 6, d = c & 63;
        int bh = b * H_ + h;
        unsigned short bv = f2bf(val);
        k_ws[(size_t)bh * S_ * 64 + (size_t)m * 64 + (((d >> 3) ^ (m & 7)) << 3) + (d & 7)] = bv;
        int ts = m >> 6, key = m & 63;
        v_tl[(((size_t)bh * NKT_ + ts) * 64 + d) * 64 + (((key >> 3) ^ (d & 7)) << 3) + (key & 7)] = bv;
    }
}

// ---------------------------------------------------------------------------
// QKV GEMM: bf16 MFMA on tile-major pre-swizzled inputs, async
// global_load_lds, double-buffered LDS, 1 barrier/k-chunk. 128x128 tile,
// BK=32, 4 waves. Epilogue scatters q natural (PRE-SCALED by log2(e)/8 so
// flash skips the per-score multiply), k row-swizzled, v tile-major.
// v19: original block mapping (both remap experiments closed: qkv remap
// neutral-to-negative, 5MB region > 4MB L2).
// ---------------------------------------------------------------------------
__global__ __launch_bounds__(256) void qkv_gemm(
    const unsigned short* __restrict__ A,     // [32][32][128][32]
    const unsigned short* __restrict__ Bt,    // [24][32][128][32]
    const float* __restrict__ bias,
    unsigned short* __restrict__ q_ws,
    unsigned short* __restrict__ k_ws,
    unsigned short* __restrict__ v_tl)
{
    __shared__ __align__(16) unsigned short As[2][4096];
    __shared__ __align__(16) unsigned short Bs[2][4096];
    const int tid = threadIdx.x, lane = tid & 63, wave = tid >> 6;
    const int wr = wave >> 1, wc = wave & 1;
    const size_t abase = (size_t)blockIdx.y * 32 * 4096;
    const size_t bbase = (size_t)blockIdx.x * 32 * 4096;

    f32x4 acc[4][4];
#pragma unroll
    for (int i = 0; i < 4; ++i)
#pragma unroll
        for (int j = 0; j < 4; ++j) acc[i][j] = (f32x4){0.f, 0.f, 0.f, 0.f};

    auto stage = [&](int kc, int buf) {
        const unsigned short* ga = A + abase + (size_t)kc * 4096;
        const unsigned short* gb = Bt + bbase + (size_t)kc * 4096;
#pragma unroll
        for (int s = 0; s < 2; ++s) {
            int seg = wave + s * 4;                       // 0..7
            gll16(ga + seg * 512 + lane * 8, &As[buf][seg * 512]);
            gll16(gb + seg * 512 + lane * 8, &Bs[buf][seg * 512]);
        }
    };

    stage(0, 0);
    __syncthreads();
    for (int kc = 0; kc < 32; ++kc) {
        if (kc + 1 < 32) stage(kc + 1, (kc + 1) & 1);
        const unsigned short* as = As[kc & 1];
        const unsigned short* bs = Bs[kc & 1];
        short8 af[4], bf4[4];
#pragma unroll
        for (int i = 0; i < 4; ++i) {
            int row = wr * 64 + i * 16 + (lane & 15);
            int ph = (lane >> 4) ^ ((row >> 1) & 3);
            af[i] = *(const short8*)&as[row * 32 + ph * 8];
        }
#pragma unroll
        for (int j = 0; j < 4; ++j) {
            int row = wc * 64 + j * 16 + (lane & 15);
            int ph = (lane >> 4) ^ ((row >> 1) & 3);
            bf4[j] = *(const short8*)&bs[row * 32 + ph * 8];
        }
#pragma unroll
        for (int i = 0; i < 4; ++i)
#pragma unroll
            for (int j = 0; j < 4; ++j)
                acc[i][j] = __builtin_amdgcn_mfma_f32_16x16x32_bf16(
                    af[i], bf4[j], acc[i][j], 0, 0, 0);
        __syncthreads();
    }

#pragma unroll
    for (int j = 0; j < 4; ++j) {
        int n = blockIdx.x * 128 + wc * 64 + j * 16 + (lane & 15);
        float bs = bias[n];
        int sel = n >> 10, h = (n >> 6) & 15, d = n & 63;
#pragma unroll
        for (int i = 0; i < 4; ++i) {
            int m = blockIdx.y * 128 + wr * 64 + i * 16 + (lane >> 4) * 4;
            int b = m >> 11, t0 = m & (T_ - 1);
            int bh = b * H_ + h;
            if (sel == 0) {
                size_t base = ((size_t)bh * T_ + t0) * 64 + d;
#pragma unroll
                for (int r = 0; r < 4; ++r)
                    q_ws[base + (size_t)r * 64] = f2bf((acc[i][j][r] + bs) * C1_);
            } else if (sel == 1) {
#pragma unroll
                for (int r = 0; r < 4; ++r) {
                    int s = MEM_ + t0 + r;
                    k_ws[(size_t)bh * S_ * 64 + (size_t)s * 64
                         + (((d >> 3) ^ (s & 7)) << 3) + (d & 7)] =
                        f2bf(acc[i][j][r] + bs);
                }
            } else {
                int s0 = MEM_ + t0, ts = s0 >> 6, key = s0 & 63;
                ushort4 pv;
                pv.x = f2bf(acc[i][j][0] + bs);
                pv.y = f2bf(acc[i][j][1] + bs);
                pv.z = f2bf(acc[i][j][2] + bs);
                pv.w = f2bf(acc[i][j][3] + bs);
                *(ushort4*)&v_tl[(((size_t)bh * NKT_ + ts) * 64 + d) * 64
                                 + (((key >> 3) ^ (d & 7)) << 3) + (key & 7)] = pv;
            }
        }
    }
}

// ---------------------------------------------------------------------------
// Proj GEMM: 64x128 tiles -> 512 blocks (2/CU, 2 waves/SIMD). 4 waves; wave w
// owns n-cols [w*32, w*32+32): 4 A-frags + 2 B-frags, 8 MFMA/chunk.
// v19: original block mapping (v17 remap suspected regressor via v18 A/B).
// ---------------------------------------------------------------------------
__global__ __launch_bounds__(256) void proj_gemm(
    const unsigned short* __restrict__ A,     // y_tl [32][32][128][32]
    const unsigned short* __restrict__ Bt,    // WtP  [8][32][128][32]
    const float* __restrict__ bias,
    float* __restrict__ out)
{
    __shared__ __align__(16) unsigned short As[2][2048];
    __shared__ __align__(16) unsigned short Bs[2][4096];
    const int tid = threadIdx.x, lane = tid & 63, wave = tid >> 6;
    const int m64 = blockIdx.y;               // 0..63
    const size_t abase = ((size_t)(m64 >> 1) * 32) * 4096 + (size_t)(m64 & 1) * 2048;
    const size_t bbase = (size_t)blockIdx.x * 32 * 4096;

    f32x4 acc[4][2];
#pragma unroll
    for (int i = 0; i < 4; ++i)
#pragma unroll
        for (int j = 0; j < 2; ++j) acc[i][j] = (f32x4){0.f, 0.f, 0.f, 0.f};

    auto stage = [&](int kc, int buf) {
        const unsigned short* ga = A + abase + (size_t)kc * 4096;
        const unsigned short* gb = Bt + bbase + (size_t)kc * 4096;
        gll16(ga + wave * 512 + lane * 8, &As[buf][wave * 512]);
        gll16(gb + wave * 512 + lane * 8, &Bs[buf][wave * 512]);
        gll16(gb + (wave + 4) * 512 + lane * 8, &Bs[buf][(wave + 4) * 512]);
    };

    stage(0, 0);
    __syncthreads();
    for (int kc = 0; kc < 32; ++kc) {
        if (kc + 1 < 32) stage(kc + 1, (kc + 1) & 1);
        const unsigned short* as = As[kc & 1];
        const unsigned short* bs = Bs[kc & 1];
        short8 af[4], bf2[2];
#pragma unroll
        for (int i = 0; i < 4; ++i) {
            int row = i * 16 + (lane & 15);           // local row in 64-tile
            int ph = (lane >> 4) ^ ((row >> 1) & 3);  // (64+row) swizzle == row swizzle
            af[i] = *(const short8*)&as[row * 32 + ph * 8];
        }
#pragma unroll
        for (int j = 0; j < 2; ++j) {
            int row = wave * 32 + j * 16 + (lane & 15);
            int ph = (lane >> 4) ^ ((row >> 1) & 3);
            bf2[j] = *(const short8*)&bs[row * 32 + ph * 8];
        }
#pragma unroll
        for (int i = 0; i < 4; ++i)
#pragma unroll
            for (int j = 0; j < 2; ++j)
                acc[i][j] = __builtin_amdgcn_mfma_f32_16x16x32_bf16(
                    af[i], bf2[j], acc[i][j], 0, 0, 0);
        __syncthreads();
    }

#pragma unroll
    for (int j = 0; j < 2; ++j) {
        int n = blockIdx.x * 128 + wave * 32 + j * 16 + (lane & 15);
        float bs = bias[n];
#pragma unroll
        for (int i = 0; i < 4; ++i) {
            int m = m64 * 64 + i * 16 + (lane >> 4) * 4;
#pragma unroll
            for (int r = 0; r < 4; ++r)
                out[(size_t)(m + r) * C_ + n] = acc[i][j][r] + bs;
        }
    }
}

// ---------------------------------------------------------------------------
// Flash attention v19 = v17 VERBATIM (measured 47.0us, WRITE 8MB, FETCH
// 13.4MB, absmax 1.953e-3). v18's "micro" edits (setprio placement, merge
// stride, staging restructure) triggered ~95MB/dispatch of scratch spill
// (WRITE_SIZE 8->102.7MB) and 2.3x'd the kernel — reverted wholesale.
// Components: XCD-aware decode (FETCH 75->13MB), denom on matrix pipe via
// ones-MFMA, running staging pointers, native exp2, setprio around whole
// tile body, top-stage discipline (REQUIRED: stage before compute).
// ---------------------------------------------------------------------------
__global__ __launch_bounds__(512, 4) void flash_mfma(
    const unsigned short* __restrict__ qg,    // [bh][t][64] natural, pre-scaled
    const unsigned short* __restrict__ kg,    // [bh][s][64] row-swizzled
    const unsigned short* __restrict__ vg,    // [bh][36][64][64] key-swizzled
    unsigned short* __restrict__ yt)          // proj-tiled [mt][kc][128][32]
{
    __shared__ __align__(16) unsigned short Ks[4][4096];
    __shared__ __align__(16) unsigned short Vs[4][4096];

    const int tid = threadIdx.x, lane = tid & 63, w = tid >> 6;   // wave 0..7
    const int grp = w >> 2, wq = w & 3;
    const int quad = lane >> 4;
    // XCD-aware decode (round-robin flat%8 -> XCD; validated by v16 FETCH)
    const int flat = blockIdx.x + 16 * (blockIdx.y + 16 * blockIdx.z);
    const int xcd = flat & 7;
    const int kk = flat >> 3;                  // 0..63
    const int a = kk & 15;
    const int g8 = (kk >> 4) * 8 + xcd;        // bh-group 0..31
    const int h = g8 & 15, b = g8 >> 4;
    const int p0 = 5 + a;                      // short tile's k-tile count
    const int nl = 36 - a;                     // long tile's k-tile count
    const int n2 = nl - p0;                    // phase-2 tiles (31-2a, odd)
    const int qt = grp ? (31 - a) : a;         // this group's primary q-tile
    const int bh = b * H_ + h;
    const size_t kgb = (size_t)bh * S_ * 64;
    const size_t vgb = (size_t)bh * NKT_ * 4096;

    // Primary Q fragment (B-operand layout: q=lane&15, d=quad*8+hf*32+j)
    short8 qfP[2], qf2[2];
    {
        const unsigned short* p = qg + ((size_t)bh * T_ + qt * 64 + wq * 16
                                        + (lane & 15)) * 64 + quad * 8;
        qfP[0] = *(const short8*)p; qfP[1] = *(const short8*)(p + 32);
        const unsigned short* q2 = qg + ((size_t)bh * T_ + (31 - a) * 64 + wq * 16
                                         + (lane & 15)) * 64 + quad * 8;
        qf2[0] = *(const short8*)q2; qf2[1] = *(const short8*)(q2 + 32);
    }

    f32x4 o[4], o2[4];
#pragma unroll
    for (int j = 0; j < 4; ++j) {
        o[j] = (f32x4){0.f, 0.f, 0.f, 0.f};
        o2[j] = (f32x4){0.f, 0.f, 0.f, 0.f};
    }
    f32x4 lv  = (f32x4){0.f, 0.f, 0.f, 0.f};   // denom, rows quad*4+r (MFMA acc)
    f32x4 lv2 = (f32x4){0.f, 0.f, 0.f, 0.f};

    short4v ones;                               // 4 x bf16 1.0
    {
        unsigned int oo1 = 0x3F803F80u;
        *(unsigned int*)&ones = oo1;
        *((unsigned int*)&ones + 1) = oo1;
    }

    // Loop-invariant LDS base pointers (ushort units).
    const unsigned short* kB0 = &Ks[0][(lane & 15) * 64 + ((quad ^ (lane & 7)) * 8)];
    const unsigned short* kB1 = &Ks[0][(lane & 15) * 64 + (((quad + 4) ^ (lane & 7)) * 8)];
    const unsigned short* vPs[4];
#pragma unroll
    for (int kb = 0; kb < 4; ++kb)
        vPs[kb] = &Vs[0][(lane & 15) * 64
                         + (((kb * 2 + (lane >> 5)) ^ (lane & 7)) * 8)
                         + (quad & 1) * 4];

    // running staging pointers (advance 4096 per staged tile)
    const unsigned short* gkC = kg + kgb + (size_t)w * 512 + (size_t)lane * 8;
    const unsigned short* gvC = vg + vgb + (size_t)w * 512 + (size_t)lane * 8;

    auto stageCur = [&](int kt) {              // 8 waves: 1 gll K + 1 gll V each
        const int bf = kt & 3;
        gll16(gkC, &Ks[bf][w * 512]);
        gll16(gvC, &Vs[bf][w * 512]);
        gkC += 4096; gvC += 4096;
    };

    const int tqP = qt * 64 + wq * 16 + (lane & 15);        // primary query row
    const int tq2 = (31 - a) * 64 + wq * 16 + (lane & 15);  // grp0 phase-2 row

    auto computeTile = [&](int kt, const short8 (&qf)[2], f32x4 (&oo)[4],
                           f32x4& lacc, bool diag, int tq) {
        const int B = (kt & 3) << 12;          // buffer offset, ushorts
        const int s0 = kt * 64;
        __builtin_amdgcn_s_setprio(1);
        short8 kA[4][2];
#pragma unroll
        for (int kb = 0; kb < 4; ++kb) {
            kA[kb][0] = *(const short8*)&kB0[B + kb * 1024];
            kA[kb][1] = *(const short8*)&kB1[B + kb * 1024];
        }
        short4v vF[4][4];
#pragma unroll
        for (int kb = 0; kb < 4; ++kb)
#pragma unroll
            for (int dblk = 0; dblk < 4; ++dblk)
                vF[kb][dblk] = *(const short4v*)&vPs[kb][B + dblk * 1024];

#pragma unroll
        for (int kb = 0; kb < 4; ++kb) {
            f32x4 z = (f32x4){0.f, 0.f, 0.f, 0.f};
            z = __builtin_amdgcn_mfma_f32_16x16x32_bf16(kA[kb][0], qf[0], z, 0, 0, 0);
            z = __builtin_amdgcn_mfma_f32_16x16x32_bf16(kA[kb][1], qf[1], z, 0, 0, 0);
            float p[4];
#pragma unroll
            for (int r = 0; r < 4; ++r) {
                float e = __builtin_amdgcn_exp2f(z[r]);   // q pre-scaled
                if (diag) {
                    int key = s0 + kb * 16 + quad * 4 + r;
                    if (key - MEM_ > tq) e = 0.f;
                }
                p[r] = e;
            }
            short4v pf;
            *(unsigned int*)&pf       = pk2bf(p[0], p[1]);
            *((unsigned int*)&pf + 1) = pk2bf(p[2], p[3]);
            // denom on the matrix pipe: row-sums of P (all lanes identical)
            lacc = __builtin_amdgcn_mfma_f32_16x16x16bf16_1k(
                pf, ones, lacc, 0, 0, 0);
#pragma unroll
            for (int dblk = 0; dblk < 4; ++dblk)
                oo[dblk] = __builtin_amdgcn_mfma_f32_16x16x16bf16_1k(
                    pf, vF[kb][dblk], oo[dblk], 0, 0, 0);
        }
        __builtin_amdgcn_s_setprio(0);
    };

    // prologue: stage tiles 0,1,2 (nl >= 21 always)
    stageCur(0); stageCur(1); stageCur(2);
    int cursor = 3;

    // Phase 1: steps s = 0..p0-1; both groups consume tile s.
    // Stage at TOP (after barrier, before compute) — required discipline.
    for (int s = 0; s < p0; ++s) {
        __syncthreads();
        if (cursor < nl && cursor <= s + 3) { stageCur(cursor); ++cursor; }
        computeTile(s, qfP, o, lv, (grp == 0) && (s == p0 - 1), tqP);
    }

    // Phase 2: long tile's remaining k-range, split even/odd between groups.
    const int nsteps2 = (n2 + 1) >> 1;
    for (int s2 = 0; s2 < nsteps2; ++s2) {
        __syncthreads();
        while (cursor < nl && cursor <= p0 + 2 * s2 + 3) { stageCur(cursor); ++cursor; }
        int t = p0 + 2 * s2 + grp;
        if (t < nl) {
            bool dg = (t == nl - 1);
            if (grp == 0) computeTile(t, qf2, o2, lv2, dg, tq2);
            else          computeTile(t, qfP, o, lv, dg, tqP);
        }
    }

    // Merge grp0's phase-2 partial into grp1 (same rows, same lane layout).
    __syncthreads();
    float* sm = (float*)&Ks[0][0];             // 256 slots x 20 f32 = 20KB
    if (grp == 0) {
        int idx = (wq * 64 + lane) * 20;
#pragma unroll
        for (int dblk = 0; dblk < 4; ++dblk)
#pragma unroll
            for (int r = 0; r < 4; ++r) sm[idx + dblk * 4 + r] = o2[dblk][r];
#pragma unroll
        for (int r = 0; r < 4; ++r) sm[idx + 16 + r] = lv2[r];
    }
    __syncthreads();
    if (grp == 1) {
        int idx = (wq * 64 + lane) * 20;
#pragma unroll
        for (int dblk = 0; dblk < 4; ++dblk)
#pragma unroll
            for (int r = 0; r < 4; ++r) o[dblk][r] += sm[idx + dblk * 4 + r];
#pragma unroll
        for (int r = 0; r < 4; ++r) lv[r] += sm[idx + 16 + r];
    }

    // epilogue: lv[r] holds the denom for row quad*4+r directly (no shfl).
    float linv[4];
#pragma unroll
    for (int r = 0; r < 4; ++r)
        linv[r] = 1.f / lv[r];
#pragma unroll
    for (int dblk = 0; dblk < 4; ++dblk) {
        int c = h * 64 + dblk * 16 + (lane & 15);
        int kc = c >> 5, cc = c & 31;
#pragma unroll
        for (int r = 0; r < 4; ++r) {
            int t = qt * 64 + wq * 16 + quad * 4 + r;
            int m = b * T_ + t;
            int mt = m >> 7, rr = m & 127;
            int p = (cc >> 3) ^ ((rr >> 1) & 3);
            yt[(((size_t)mt * 32 + kc) << 12) + (rr << 5) + p * 8 + (cc & 7)] =
                f2bf(o[dblk][r] * linv[r]);
        }
    }
}

extern "C" void kernel_launch(void* const* d_in, const int* in_sizes, int n_in,
                              void* d_out, int out_size, void* d_ws, size_t ws_size,
                              hipStream_t stream) {
    (void)in_sizes; (void)n_in; (void)out_size; (void)ws_size;
    const float* x      = (const float*)d_in[0];
    const float* ext    = (const float*)d_in[1];
    const float* W_attn = (const float*)d_in[2];
    const float* b_attn = (const float*)d_in[3];
    const float* W_proj = (const float*)d_in[4];
    const float* b_proj = (const float*)d_in[5];
    float* out = (float*)d_out;

    unsigned short* x_tl  = (unsigned short*)d_ws;           // [32][32][128][32]
    unsigned short* WtA   = x_tl + 4194304;                  // [24][32][128][32]
    unsigned short* WtP   = WtA + 3145728;                   // [8][32][128][32]
    unsigned short* q_ws  = WtP + 1048576;                   // [bh][t][64] pre-scaled
    unsigned short* k_ws  = q_ws + 4194304;                  // [bh][s][64] swz
    unsigned short* v_tl  = k_ws + 4718592;                  // [bh][36][64][64] swz
    unsigned short* y_tl  = v_tl + 4718592;                  // [32][32][128][32]

    dim3 blk(256);
    prep_all<<<7168, blk, 0, stream>>>(x, W_attn, W_proj, ext,
                                       x_tl, WtA, WtP, k_ws, v_tl);
    qkv_gemm<<<dim3(24, 32), blk, 0, stream>>>(
        x_tl, WtA, b_attn, q_ws, k_ws, v_tl);
    flash_mfma<<<dim3(16, H_, B_), dim3(512), 0, stream>>>(q_ws, k_ws, v_tl, y_tl);
    proj_gemm<<<dim3(8, 64), blk, 0, stream>>>(y_tl, WtP, b_proj, out);
}

// Round 13
// 185.530 us; speedup vs baseline: 1.3388x; 1.0036x over previous
//
#include <hip/hip_runtime.h>

#define B_    2
#define T_    2048
#define C_    1024
#define H_    16
#define HD_   64
#define MEM_  256
#define S_    2304   // MEM + T
#define NKT_  36     // S_/64 k-tiles

typedef __attribute__((ext_vector_type(8))) short short8;   // 8 bf16 = 4 VGPRs
typedef __attribute__((ext_vector_type(4))) short short4v;  // 4 bf16 = 2 VGPRs
typedef __attribute__((ext_vector_type(4))) float f32x4;

// round-half-up bf16 (2 VALU ops; tie behavior irrelevant here)
__device__ __forceinline__ unsigned short f2bf(float x) {
    return (unsigned short)((__float_as_uint(x) + 0x8000u) >> 16);
}

// pack 2 floats -> 2 bf16 in one VGPR (round-half-up): 2 adds + 1 v_perm
__device__ __forceinline__ unsigned int pk2bf(float lo, float hi) {
    unsigned int a = __float_as_uint(lo) + 0x8000u;
    unsigned int b = __float_as_uint(hi) + 0x8000u;
    return __builtin_amdgcn_perm(b, a, 0x07060302);  // {b.hi16, a.hi16}
}

typedef const __attribute__((address_space(1))) unsigned int* gp_t;
typedef __attribute__((address_space(3))) unsigned int* lp_t;

// async global->LDS, 16B/lane. g per-lane (base + lane*8 ushorts), l wave-uniform.
__device__ __forceinline__ void gll16(const unsigned short* g, unsigned short* l) {
    __builtin_amdgcn_global_load_lds((gp_t)g, (lp_t)l, 16, 0, 0);
}

#define C1_ 0.18033688011112042f   // log2(e)/sqrt(64), pre-folded into q

// ---------------------------------------------------------------------------
// Merged prep: job by flat blockIdx.
//  [0,4096)       convert x  -> x_tl  tile-major swizzled [mt][kc][128][32]
//  [4096,4864)    transpose W_attn -> WtA [nt][kc][128][32]
//  [4864,5120)    transpose W_proj -> WtP
//  [5120,7168)    ext_mem -> k_ws rows 0..MEM (row-swz), v_tl tiles 0..3 (swz)
// ---------------------------------------------------------------------------
__global__ __launch_bounds__(256) void prep_all(
    const float* __restrict__ x, const float* __restrict__ Wa,
    const float* __restrict__ Wp, const float* __restrict__ ext,
    unsigned short* __restrict__ x_tl, unsigned short* __restrict__ WtA,
    unsigned short* __restrict__ WtP, unsigned short* __restrict__ k_ws,
    unsigned short* __restrict__ v_tl)
{
    __shared__ float L[64][65];
    const int bid = blockIdx.x, tid = threadIdx.x;
    if (bid < 4096) {
        int i = bid * 256 + tid;                  // over 1,048,576 float4
        int c = (i & 255) * 4;
        int m = i >> 8;
        float4 v = ((const float4*)x)[i];
        ushort4 o;
        o.x = f2bf(v.x); o.y = f2bf(v.y); o.z = f2bf(v.z); o.w = f2bf(v.w);
        int mt = m >> 7, r = m & 127, kc = c >> 5, cc = c & 31;
        int p = (cc >> 3) ^ ((r >> 1) & 3);
        *(ushort4*)&x_tl[(((size_t)mt * 32 + kc) << 12) + (r << 5) + p * 8 + (cc & 7)] = o;
    } else if (bid < 5120) {
        const float* in; unsigned short* out; int Cc, r0, c0;
        if (bid < 4864) {
            int r = bid - 4096; in = Wa; out = WtA; Cc = 3 * C_;
            c0 = (r % 48) * 64; r0 = (r / 48) * 64;
        } else {
            int r = bid - 4864; in = Wp; out = WtP; Cc = C_;
            c0 = (r & 15) * 64; r0 = (r >> 4) * 64;
        }
        const int jj = tid >> 4;
        const int i4 = (tid & 15) * 4;
#pragma unroll
        for (int t = 0; t < 4; ++t) {
            int j = jj + t * 16;
            float4 v = *(const float4*)(in + (size_t)(r0 + j) * Cc + c0 + i4);
            L[i4 + 0][j] = v.x; L[i4 + 1][j] = v.y;
            L[i4 + 2][j] = v.z; L[i4 + 3][j] = v.w;
        }
        __syncthreads();
#pragma unroll
        for (int t = 0; t < 4; ++t) {
            int n = c0 + jj + t * 16;
            int k = r0 + i4;
            ushort4 o;
            o.x = f2bf(L[jj + t * 16][i4 + 0]); o.y = f2bf(L[jj + t * 16][i4 + 1]);
            o.z = f2bf(L[jj + t * 16][i4 + 2]); o.w = f2bf(L[jj + t * 16][i4 + 3]);
            int nt = n >> 7, r = n & 127, kc = k >> 5, cc = k & 31;
            int p = (cc >> 3) ^ ((r >> 1) & 3);
            *(ushort4*)&out[(((size_t)nt * 32 + kc) << 12) + (r << 5) + p * 8 + (cc & 7)] = o;
        }
    } else {
        int idx = (bid - 5120) * 256 + tid;       // < B*MEM*C = 524288
        float val = ext[idx];
        int c = idx & (C_ - 1), m = (idx >> 10) & (MEM_ - 1), b = idx >> 18;
        int h = c >> 6, d = c & 63;
        int bh = b * H_ + h;
        unsigned short bv = f2bf(val);
        k_ws[(size_t)bh * S_ * 64 + (size_t)m * 64 + (((d >> 3) ^ (m & 7)) << 3) + (d & 7)] = bv;
        int ts = m >> 6, key = m & 63;
        v_tl[(((size_t)bh * NKT_ + ts) * 64 + d) * 64 + (((key >> 3) ^ (d & 7)) << 3) + (key & 7)] = bv;
    }
}

// ---------------------------------------------------------------------------
// QKV GEMM: bf16 MFMA on tile-major pre-swizzled inputs, async
// global_load_lds, double-buffered LDS, 1 barrier/k-chunk. 128x128 tile,
// BK=32, 4 waves. Epilogue scatters q natural (PRE-SCALED by log2(e)/8 so
// flash skips the per-score multiply), k row-swizzled, v tile-major.
// Original block mapping (remap experiments closed as neutral/negative).
// ---------------------------------------------------------------------------
__global__ __launch_bounds__(256) void qkv_gemm(
    const unsigned short* __restrict__ A,     // [32][32][128][32]
    const unsigned short* __restrict__ Bt,    // [24][32][128][32]
    const float* __restrict__ bias,
    unsigned short* __restrict__ q_ws,
    unsigned short* __restrict__ k_ws,
    unsigned short* __restrict__ v_tl)
{
    __shared__ __align__(16) unsigned short As[2][4096];
    __shared__ __align__(16) unsigned short Bs[2][4096];
    const int tid = threadIdx.x, lane = tid & 63, wave = tid >> 6;
    const int wr = wave >> 1, wc = wave & 1;
    const size_t abase = (size_t)blockIdx.y * 32 * 4096;
    const size_t bbase = (size_t)blockIdx.x * 32 * 4096;

    f32x4 acc[4][4];
#pragma unroll
    for (int i = 0; i < 4; ++i)
#pragma unroll
        for (int j = 0; j < 4; ++j) acc[i][j] = (f32x4){0.f, 0.f, 0.f, 0.f};

    auto stage = [&](int kc, int buf) {
        const unsigned short* ga = A + abase + (size_t)kc * 4096;
        const unsigned short* gb = Bt + bbase + (size_t)kc * 4096;
#pragma unroll
        for (int s = 0; s < 2; ++s) {
            int seg = wave + s * 4;                       // 0..7
            gll16(ga + seg * 512 + lane * 8, &As[buf][seg * 512]);
            gll16(gb + seg * 512 + lane * 8, &Bs[buf][seg * 512]);
        }
    };

    stage(0, 0);
    __syncthreads();
    for (int kc = 0; kc < 32; ++kc) {
        if (kc + 1 < 32) stage(kc + 1, (kc + 1) & 1);
        const unsigned short* as = As[kc & 1];
        const unsigned short* bs = Bs[kc & 1];
        short8 af[4], bf4[4];
#pragma unroll
        for (int i = 0; i < 4; ++i) {
            int row = wr * 64 + i * 16 + (lane & 15);
            int ph = (lane >> 4) ^ ((row >> 1) & 3);
            af[i] = *(const short8*)&as[row * 32 + ph * 8];
        }
#pragma unroll
        for (int j = 0; j < 4; ++j) {
            int row = wc * 64 + j * 16 + (lane & 15);
            int ph = (lane >> 4) ^ ((row >> 1) & 3);
            bf4[j] = *(const short8*)&bs[row * 32 + ph * 8];
        }
#pragma unroll
        for (int i = 0; i < 4; ++i)
#pragma unroll
            for (int j = 0; j < 4; ++j)
                acc[i][j] = __builtin_amdgcn_mfma_f32_16x16x32_bf16(
                    af[i], bf4[j], acc[i][j], 0, 0, 0);
        __syncthreads();
    }

#pragma unroll
    for (int j = 0; j < 4; ++j) {
        int n = blockIdx.x * 128 + wc * 64 + j * 16 + (lane & 15);
        float bs = bias[n];
        int sel = n >> 10, h = (n >> 6) & 15, d = n & 63;
#pragma unroll
        for (int i = 0; i < 4; ++i) {
            int m = blockIdx.y * 128 + wr * 64 + i * 16 + (lane >> 4) * 4;
            int b = m >> 11, t0 = m & (T_ - 1);
            int bh = b * H_ + h;
            if (sel == 0) {
                size_t base = ((size_t)bh * T_ + t0) * 64 + d;
#pragma unroll
                for (int r = 0; r < 4; ++r)
                    q_ws[base + (size_t)r * 64] = f2bf((acc[i][j][r] + bs) * C1_);
            } else if (sel == 1) {
#pragma unroll
                for (int r = 0; r < 4; ++r) {
                    int s = MEM_ + t0 + r;
                    k_ws[(size_t)bh * S_ * 64 + (size_t)s * 64
                         + (((d >> 3) ^ (s & 7)) << 3) + (d & 7)] =
                        f2bf(acc[i][j][r] + bs);
                }
            } else {
                int s0 = MEM_ + t0, ts = s0 >> 6, key = s0 & 63;
                ushort4 pv;
                pv.x = f2bf(acc[i][j][0] + bs);
                pv.y = f2bf(acc[i][j][1] + bs);
                pv.z = f2bf(acc[i][j][2] + bs);
                pv.w = f2bf(acc[i][j][3] + bs);
                *(ushort4*)&v_tl[(((size_t)bh * NKT_ + ts) * 64 + d) * 64
                                 + (((key >> 3) ^ (d & 7)) << 3) + (key & 7)] = pv;
            }
        }
    }
}

// ---------------------------------------------------------------------------
// Proj GEMM: 64x128 tiles -> 512 blocks (2/CU, 2 waves/SIMD). 4 waves; wave w
// owns n-cols [w*32, w*32+32): 4 A-frags + 2 B-frags, 8 MFMA/chunk.
// Original block mapping.
// ---------------------------------------------------------------------------
__global__ __launch_bounds__(256) void proj_gemm(
    const unsigned short* __restrict__ A,     // y_tl [32][32][128][32]
    const unsigned short* __restrict__ Bt,    // WtP  [8][32][128][32]
    const float* __restrict__ bias,
    float* __restrict__ out)
{
    __shared__ __align__(16) unsigned short As[2][2048];
    __shared__ __align__(16) unsigned short Bs[2][4096];
    const int tid = threadIdx.x, lane = tid & 63, wave = tid >> 6;
    const int m64 = blockIdx.y;               // 0..63
    const size_t abase = ((size_t)(m64 >> 1) * 32) * 4096 + (size_t)(m64 & 1) * 2048;
    const size_t bbase = (size_t)blockIdx.x * 32 * 4096;

    f32x4 acc[4][2];
#pragma unroll
    for (int i = 0; i < 4; ++i)
#pragma unroll
        for (int j = 0; j < 2; ++j) acc[i][j] = (f32x4){0.f, 0.f, 0.f, 0.f};

    auto stage = [&](int kc, int buf) {
        const unsigned short* ga = A + abase + (size_t)kc * 4096;
        const unsigned short* gb = Bt + bbase + (size_t)kc * 4096;
        gll16(ga + wave * 512 + lane * 8, &As[buf][wave * 512]);
        gll16(gb + wave * 512 + lane * 8, &Bs[buf][wave * 512]);
        gll16(gb + (wave + 4) * 512 + lane * 8, &Bs[buf][(wave + 4) * 512]);
    };

    stage(0, 0);
    __syncthreads();
    for (int kc = 0; kc < 32; ++kc) {
        if (kc + 1 < 32) stage(kc + 1, (kc + 1) & 1);
        const unsigned short* as = As[kc & 1];
        const unsigned short* bs = Bs[kc & 1];
        short8 af[4], bf2[2];
#pragma unroll
        for (int i = 0; i < 4; ++i) {
            int row = i * 16 + (lane & 15);           // local row in 64-tile
            int ph = (lane >> 4) ^ ((row >> 1) & 3);  // (64+row) swizzle == row swizzle
            af[i] = *(const short8*)&as[row * 32 + ph * 8];
        }
#pragma unroll
        for (int j = 0; j < 2; ++j) {
            int row = wave * 32 + j * 16 + (lane & 15);
            int ph = (lane >> 4) ^ ((row >> 1) & 3);
            bf2[j] = *(const short8*)&bs[row * 32 + ph * 8];
        }
#pragma unroll
        for (int i = 0; i < 4; ++i)
#pragma unroll
            for (int j = 0; j < 2; ++j)
                acc[i][j] = __builtin_amdgcn_mfma_f32_16x16x32_bf16(
                    af[i], bf2[j], acc[i][j], 0, 0, 0);
        __syncthreads();
    }

#pragma unroll
    for (int j = 0; j < 2; ++j) {
        int n = blockIdx.x * 128 + wave * 32 + j * 16 + (lane & 15);
        float bs = bias[n];
#pragma unroll
        for (int i = 0; i < 4; ++i) {
            int m = m64 * 64 + i * 16 + (lane >> 4) * 4;
#pragma unroll
            for (int r = 0; r < 4; ++r)
                out[(size_t)(m + r) * C_ + n] = acc[i][j][r] + bs;
        }
    }
}

// ---------------------------------------------------------------------------
// Flash attention v20 = v19 + phase-1 superstep (2 k-tiles per barrier).
// v19 counters: MfmaUtil 31%, VALU 42%, HBM 5.8% — nothing saturated;
// dependency-latency-bound at the 16 waves/CU concurrency ceiling. Phase 1
// ran 1 tile/barrier; merging 2 per barrier (a) halves phase-1 barrier
// drains, (b) doubles the compiler's scheduling window so tile s+1's
// ds_reads issue under tile s's MFMA/exp chain. Buffer algebra: superstep s
// stages s+2,s+3 (bufs distinct from computed s,s+1 mod 4; staged buffers
// were last read >=1 barrier ago). Stage-before-compute law preserved.
// Per-wave arithmetic order identical to v19 -> output bit-identical
// (absmax fingerprint 1.953e-3 is the correctness canary; WRITE_SIZE 8MB
// is the spill canary).
// ---------------------------------------------------------------------------
__global__ __launch_bounds__(512, 4) void flash_mfma(
    const unsigned short* __restrict__ qg,    // [bh][t][64] natural, pre-scaled
    const unsigned short* __restrict__ kg,    // [bh][s][64] row-swizzled
    const unsigned short* __restrict__ vg,    // [bh][36][64][64] key-swizzled
    unsigned short* __restrict__ yt)          // proj-tiled [mt][kc][128][32]
{
    __shared__ __align__(16) unsigned short Ks[4][4096];
    __shared__ __align__(16) unsigned short Vs[4][4096];

    const int tid = threadIdx.x, lane = tid & 63, w = tid >> 6;   // wave 0..7
    const int grp = w >> 2, wq = w & 3;
    const int quad = lane >> 4;
    // XCD-aware decode (round-robin flat%8 -> XCD; validated by v16 FETCH)
    const int flat = blockIdx.x + 16 * (blockIdx.y + 16 * blockIdx.z);
    const int xcd = flat & 7;
    const int kk = flat >> 3;                  // 0..63
    const int a = kk & 15;
    const int g8 = (kk >> 4) * 8 + xcd;        // bh-group 0..31
    const int h = g8 & 15, b = g8 >> 4;
    const int p0 = 5 + a;                      // short tile's k-tile count
    const int nl = 36 - a;                     // long tile's k-tile count
    const int n2 = nl - p0;                    // phase-2 tiles (31-2a, odd)
    const int qt = grp ? (31 - a) : a;         // this group's primary q-tile
    const int bh = b * H_ + h;
    const size_t kgb = (size_t)bh * S_ * 64;
    const size_t vgb = (size_t)bh * NKT_ * 4096;

    // Primary Q fragment (B-operand layout: q=lane&15, d=quad*8+hf*32+j)
    short8 qfP[2], qf2[2];
    {
        const unsigned short* p = qg + ((size_t)bh * T_ + qt * 64 + wq * 16
                                        + (lane & 15)) * 64 + quad * 8;
        qfP[0] = *(const short8*)p; qfP[1] = *(const short8*)(p + 32);
        const unsigned short* q2 = qg + ((size_t)bh * T_ + (31 - a) * 64 + wq * 16
                                         + (lane & 15)) * 64 + quad * 8;
        qf2[0] = *(const short8*)q2; qf2[1] = *(const short8*)(q2 + 32);
    }

    f32x4 o[4], o2[4];
#pragma unroll
    for (int j = 0; j < 4; ++j) {
        o[j] = (f32x4){0.f, 0.f, 0.f, 0.f};
        o2[j] = (f32x4){0.f, 0.f, 0.f, 0.f};
    }
    f32x4 lv  = (f32x4){0.f, 0.f, 0.f, 0.f};   // denom, rows quad*4+r (MFMA acc)
    f32x4 lv2 = (f32x4){0.f, 0.f, 0.f, 0.f};

    short4v ones;                               // 4 x bf16 1.0
    {
        unsigned int oo1 = 0x3F803F80u;
        *(unsigned int*)&ones = oo1;
        *((unsigned int*)&ones + 1) = oo1;
    }

    // Loop-invariant LDS base pointers (ushort units).
    const unsigned short* kB0 = &Ks[0][(lane & 15) * 64 + ((quad ^ (lane & 7)) * 8)];
    const unsigned short* kB1 = &Ks[0][(lane & 15) * 64 + (((quad + 4) ^ (lane & 7)) * 8)];
    const unsigned short* vPs[4];
#pragma unroll
    for (int kb = 0; kb < 4; ++kb)
        vPs[kb] = &Vs[0][(lane & 15) * 64
                         + (((kb * 2 + (lane >> 5)) ^ (lane & 7)) * 8)
                         + (quad & 1) * 4];

    // running staging pointers (advance 4096 per staged tile)
    const unsigned short* gkC = kg + kgb + (size_t)w * 512 + (size_t)lane * 8;
    const unsigned short* gvC = vg + vgb + (size_t)w * 512 + (size_t)lane * 8;

    auto stageCur = [&](int kt) {              // 8 waves: 1 gll K + 1 gll V each
        const int bf = kt & 3;
        gll16(gkC, &Ks[bf][w * 512]);
        gll16(gvC, &Vs[bf][w * 512]);
        gkC += 4096; gvC += 4096;
    };

    const int tqP = qt * 64 + wq * 16 + (lane & 15);        // primary query row
    const int tq2 = (31 - a) * 64 + wq * 16 + (lane & 15);  // grp0 phase-2 row

    auto computeTile = [&](int kt, const short8 (&qf)[2], f32x4 (&oo)[4],
                           f32x4& lacc, bool diag, int tq) {
        const int B = (kt & 3) << 12;          // buffer offset, ushorts
        const int s0 = kt * 64;
        __builtin_amdgcn_s_setprio(1);
        short8 kA[4][2];
#pragma unroll
        for (int kb = 0; kb < 4; ++kb) {
            kA[kb][0] = *(const short8*)&kB0[B + kb * 1024];
            kA[kb][1] = *(const short8*)&kB1[B + kb * 1024];
        }
        short4v vF[4][4];
#pragma unroll
        for (int kb = 0; kb < 4; ++kb)
#pragma unroll
            for (int dblk = 0; dblk < 4; ++dblk)
                vF[kb][dblk] = *(const short4v*)&vPs[kb][B + dblk * 1024];

#pragma unroll
        for (int kb = 0; kb < 4; ++kb) {
            f32x4 z = (f32x4){0.f, 0.f, 0.f, 0.f};
            z = __builtin_amdgcn_mfma_f32_16x16x32_bf16(kA[kb][0], qf[0], z, 0, 0, 0);
            z = __builtin_amdgcn_mfma_f32_16x16x32_bf16(kA[kb][1], qf[1], z, 0, 0, 0);
            float p[4];
#pragma unroll
            for (int r = 0; r < 4; ++r) {
                float e = __builtin_amdgcn_exp2f(z[r]);   // q pre-scaled
                if (diag) {
                    int key = s0 + kb * 16 + quad * 4 + r;
                    if (key - MEM_ > tq) e = 0.f;
                }
                p[r] = e;
            }
            short4v pf;
            *(unsigned int*)&pf       = pk2bf(p[0], p[1]);
            *((unsigned int*)&pf + 1) = pk2bf(p[2], p[3]);
            // denom on the matrix pipe: row-sums of P (all lanes identical)
            lacc = __builtin_amdgcn_mfma_f32_16x16x16bf16_1k(
                pf, ones, lacc, 0, 0, 0);
#pragma unroll
            for (int dblk = 0; dblk < 4; ++dblk)
                oo[dblk] = __builtin_amdgcn_mfma_f32_16x16x16bf16_1k(
                    pf, vF[kb][dblk], oo[dblk], 0, 0, 0);
        }
        __builtin_amdgcn_s_setprio(0);
    };

    // prologue: stage tiles 0,1,2 (nl >= 21 always)
    stageCur(0); stageCur(1); stageCur(2);
    int cursor = 3;

    // Phase 1 SUPERSTEP: 2 tiles per barrier. At superstep s: stage up to 2
    // tiles (cap s+3 -> never aliases bufs s..s+3), compute s and s+1.
    // Stage at TOP (after barrier, before compute) — required discipline.
    for (int s = 0; s < p0; s += 2) {
        __syncthreads();
        if (cursor < nl && cursor <= s + 3) { stageCur(cursor); ++cursor; }
        if (cursor < nl && cursor <= s + 3) { stageCur(cursor); ++cursor; }
        computeTile(s, qfP, o, lv, (grp == 0) && (s == p0 - 1), tqP);
        if (s + 1 < p0)
            computeTile(s + 1, qfP, o, lv, (grp == 0) && (s + 1 == p0 - 1), tqP);
    }

    // Phase 2: long tile's remaining k-range, split even/odd between groups.
    const int nsteps2 = (n2 + 1) >> 1;
    for (int s2 = 0; s2 < nsteps2; ++s2) {
        __syncthreads();
        while (cursor < nl && cursor <= p0 + 2 * s2 + 3) { stageCur(cursor); ++cursor; }
        int t = p0 + 2 * s2 + grp;
        if (t < nl) {
            bool dg = (t == nl - 1);
            if (grp == 0) computeTile(t, qf2, o2, lv2, dg, tq2);
            else          computeTile(t, qfP, o, lv, dg, tqP);
        }
    }

    // Merge grp0's phase-2 partial into grp1 (same rows, same lane layout).
    __syncthreads();
    float* sm = (float*)&Ks[0][0];             // 256 slots x 20 f32 = 20KB
    if (grp == 0) {
        int idx = (wq * 64 + lane) * 20;
#pragma unroll
        for (int dblk = 0; dblk < 4; ++dblk)
#pragma unroll
            for (int r = 0; r < 4; ++r) sm[idx + dblk * 4 + r] = o2[dblk][r];
#pragma unroll
        for (int r = 0; r < 4; ++r) sm[idx + 16 + r] = lv2[r];
    }
    __syncthreads();
    if (grp == 1) {
        int idx = (wq * 64 + lane) * 20;
#pragma unroll
        for (int dblk = 0; dblk < 4; ++dblk)
#pragma unroll
            for (int r = 0; r < 4; ++r) o[dblk][r] += sm[idx + dblk * 4 + r];
#pragma unroll
        for (int r = 0; r < 4; ++r) lv[r] += sm[idx + 16 + r];
    }

    // epilogue: lv[r] holds the denom for row quad*4+r directly (no shfl).
    float linv[4];
#pragma unroll
    for (int r = 0; r < 4; ++r)
        linv[r] = 1.f / lv[r];
#pragma unroll
    for (int dblk = 0; dblk < 4; ++dblk) {
        int c = h * 64 + dblk * 16 + (lane & 15);
        int kc = c >> 5, cc = c & 31;
#pragma unroll
        for (int r = 0; r < 4; ++r) {
            int t = qt * 64 + wq * 16 + quad * 4 + r;
            int m = b * T_ + t;
            int mt = m >> 7, rr = m & 127;
            int p = (cc >> 3) ^ ((rr >> 1) & 3);
            yt[(((size_t)mt * 32 + kc) << 12) + (rr << 5) + p * 8 + (cc & 7)] =
                f2bf(o[dblk][r] * linv[r]);
        }
    }
}

extern "C" void kernel_launch(void* const* d_in, const int* in_sizes, int n_in,
                              void* d_out, int out_size, void* d_ws, size_t ws_size,
                              hipStream_t stream) {
    (void)in_sizes; (void)n_in; (void)out_size; (void)ws_size;
    const float* x      = (const float*)d_in[0];
    const float* ext    = (const float*)d_in[1];
    const float* W_attn = (const float*)d_in[2];
    const float* b_attn = (const float*)d_in[3];
    const float* W_proj = (const float*)d_in[4];
    const float* b_proj = (const float*)d_in[5];
    float* out = (float*)d_out;

    unsigned short* x_tl  = (unsigned short*)d_ws;           // [32][32][128][32]
    unsigned short* WtA   = x_tl + 4194304;                  // [24][32][128][32]
    unsigned short* WtP   = WtA + 3145728;                   // [8][32][128][32]
    unsigned short* q_ws  = WtP + 1048576;                   // [bh][t][64] pre-scaled
    unsigned short* k_ws  = q_ws + 4194304;                  // [bh][s][64] swz
    unsigned short* v_tl  = k_ws + 4718592;                  // [bh][36][64][64] swz
    unsigned short* y_tl  = v_tl + 4718592;                  // [32][32][128][32]

    dim3 blk(256);
    prep_all<<<7168, blk, 0, stream>>>(x, W_attn, W_proj, ext,
                                       x_tl, WtA, WtP, k_ws, v_tl);
    qkv_gemm<<<dim3(24, 32), blk, 0, stream>>>(
        x_tl, WtA, b_attn, q_ws, k_ws, v_tl);
    flash_mfma<<<dim3(16, H_, B_), dim3(512), 0, stream>>>(q_ws, k_ws, v_tl, y_tl);
    proj_gemm<<<dim3(8, 64), blk, 0, stream>>>(y_tl, WtP, b_proj, out);
}